// Round 7
// baseline (16490.674 us; speedup 1.0000x reference)
//
#include <hip/hip_runtime.h>
#include <stdint.h>

// BiGRU scan, H=1024. Round 7:
//  - Scan: R1 core (171x256, lb(256,1), 204 VGPR) with ONE change: p/q gate
//    split. p-dots no longer wait on q tags (q checked after p-publish; q poll
//    loads issued pre-dots so latency hides under the 144-MAC dot phase).
//  - gh GEMM: prep kernel writes bf16 hi/lo planes of h0 ONCE (kills the 25x
//    redundant divergent gather of R5), then a 128x128 MFMA GEMM with pure
//    vector staging. Identical summation order to R5 => absmax must remain
//    exactly 0.015625. Falls back to R5's proven gh_gemm_mfma if ws too small.

#define H    1024
#define HH   1025
#define N3   3075
#define TQ   512
#define TP   4096
#define MTOT 4608
#define GTOT 2050
#define GH_ELEMS (MTOT * N3)
#define AKP  1056                               // padded K (33 chunks of 32)
#define ATOT ((size_t)MTOT * 2 * AKP)           // shorts per plane (hi or lo)

typedef unsigned long long ull;
typedef __attribute__((ext_vector_type(8))) short short8;
typedef __attribute__((ext_vector_type(4))) float f32x4;

__device__ __forceinline__ float sigm(float x) { return 1.f / (1.f + __expf(-x)); }
__device__ __forceinline__ float fast_tanh(float x) {
    float e = __expf(2.f * x);
    return (e - 1.f) / (e + 1.f);
}
__device__ __forceinline__ unsigned short f2bf(float f) {
    unsigned u = __float_as_uint(f);
    unsigned r = (u + 0x7FFFu + ((u >> 16) & 1u)) >> 16;
    return (unsigned short)r;
}
__device__ __forceinline__ float bf2f(unsigned short h) {
    return __uint_as_float(((unsigned)h) << 16);
}

#define ALOAD(p)     __hip_atomic_load((p), __ATOMIC_RELAXED, __HIP_MEMORY_SCOPE_AGENT)
#define ASTORE(p, v) __hip_atomic_store((p), (v), __ATOMIC_RELAXED, __HIP_MEMORY_SCOPE_AGENT)

// ---------------------------------------------------------------------------
// Prep: h0 -> bf16 hi/lo planes, padded to AKP. Gather math identical to R5's
// proven in-GEMM A-stage. abf[hi: rowid*AKP + k], lo plane at +ATOT.
// rowid = m*2 + dir.
// ---------------------------------------------------------------------------
__global__ __launch_bounds__(256) void prep_abf(
    const float* __restrict__ eq, const float* __restrict__ ep,
    const float* __restrict__ fs, const float* __restrict__ fe,
    unsigned short* __restrict__ abf)
{
    const int K8 = AKP / 8;                    // 132 groups of 8 k
    int idx = blockIdx.x * 256 + threadIdx.x;
    int rowid = idx / K8;
    if (rowid >= MTOT * 2) return;
    int k0 = (idx - rowid * K8) * 8;
    int dir = rowid & 1;
    int m = rowid >> 1;
    bool isq = m < TQ;
    const float* e = isq ? eq : ep;
    int t = isq ? m : m - TQ;

    short8 hi, lo;
#pragma unroll
    for (int j = 0; j < 8; j++) {
        int gk = k0 + j;
        float v = 0.f;
        if (gk < HH) {
            if (dir == 0)            v = e[(size_t)t * 2048 + gk];
            else if (gk < 1023)      v = e[(size_t)t * 2048 + 1025 + gk];
            else if (!isq)           v = (gk == 1023) ? fs[t] : fe[t];
        }
        unsigned short h = f2bf(v);
        hi[j] = (short)h;
        lo[j] = (short)f2bf(v - bf2f(h));
    }
    size_t base = (size_t)rowid * AKP + k0;    // 16B-aligned (k0 mult of 8)
    *(short8*)&abf[base] = hi;
    *(short8*)&abf[ATOT + base] = lo;
}

// ---------------------------------------------------------------------------
// Fast MFMA gh GEMM: 128M x 128N tile, K-chunks of 32. Wave w owns rows
// 32w..32w+31 (2 row-tiles); 8 col-tiles; acc[2][8] f32x4 (64 VGPR).
// LDS row stride 40 shorts (80 B) keeps ds_read_b128 aliasing benign (R5).
// ---------------------------------------------------------------------------
__global__ __launch_bounds__(256, 2) void gh_gemm_fast(
    const unsigned short* __restrict__ abf,
    const float* __restrict__ Whh_f, const float* __restrict__ bhh_f,
    const float* __restrict__ Whh_b, const float* __restrict__ bhh_b,
    float* __restrict__ ghf, float* __restrict__ ghb)
{
    const int dir = blockIdx.z;
    const float* W  = dir ? Whh_b : Whh_f;
    const float* bh = dir ? bhh_b : bhh_f;
    float* gh = dir ? ghb : ghf;
    const int n0 = blockIdx.x * 128;
    const int m0 = blockIdx.y * 128;
    const int tid = threadIdx.x, wave = tid >> 6, lane = tid & 63;

    __shared__ __align__(16) unsigned short Ah[128][40];
    __shared__ __align__(16) unsigned short Al[128][40];
    __shared__ __align__(16) unsigned short Bs[128][40];

    f32x4 acc[2][8];
#pragma unroll
    for (int rt = 0; rt < 2; rt++)
#pragma unroll
        for (int c = 0; c < 8; c++) acc[rt][c] = (f32x4){0.f, 0.f, 0.f, 0.f};

    for (int kc = 0; kc < 33; kc++) {
        const int k0 = kc * 32;
        // ---- stage A hi/lo: thread -> row tid>>1, half (tid&1)*16 ----
        {
            int r = tid >> 1, h16 = (tid & 1) * 16;
            size_t arow = ((size_t)(m0 + r) * 2 + dir) * AKP + k0 + h16;
            short8 v0 = *(const short8*)&abf[arow];
            short8 v1 = *(const short8*)&abf[arow + 8];
            *(short8*)&Ah[r][h16]     = v0;
            *(short8*)&Ah[r][h16 + 8] = v1;
            short8 u0 = *(const short8*)&abf[ATOT + arow];
            short8 u1 = *(const short8*)&abf[ATOT + arow + 8];
            *(short8*)&Al[r][h16]     = u0;
            *(short8*)&Al[r][h16 + 8] = u1;
        }
        // ---- stage B (coalesced scalar convert, proven in R5) ----
#pragma unroll
        for (int u = 0; u < 16; u++) {
            int lin = u * 256 + tid;
            int r = lin >> 5, k = lin & 31;
            int gr = n0 + r, gk = k0 + k;
            float v = (gr < N3 && gk < HH) ? W[(size_t)gr * HH + gk] : 0.f;
            Bs[r][k] = f2bf(v);
        }
        __syncthreads();

        const int rA0 = wave * 32 + (lane & 15);
        const int ko  = (lane >> 4) * 8;
        short8 ah0 = *(const short8*)&Ah[rA0][ko];
        short8 ah1 = *(const short8*)&Ah[rA0 + 16][ko];
        short8 al0 = *(const short8*)&Al[rA0][ko];
        short8 al1 = *(const short8*)&Al[rA0 + 16][ko];
#pragma unroll
        for (int c = 0; c < 8; c++) {
            short8 b = *(const short8*)&Bs[c * 16 + (lane & 15)][ko];
            acc[0][c] = __builtin_amdgcn_mfma_f32_16x16x32_bf16(ah0, b, acc[0][c], 0, 0, 0);
            acc[0][c] = __builtin_amdgcn_mfma_f32_16x16x32_bf16(al0, b, acc[0][c], 0, 0, 0);
            acc[1][c] = __builtin_amdgcn_mfma_f32_16x16x32_bf16(ah1, b, acc[1][c], 0, 0, 0);
            acc[1][c] = __builtin_amdgcn_mfma_f32_16x16x32_bf16(al1, b, acc[1][c], 0, 0, 0);
        }
        __syncthreads();
    }

    // ---- epilogue: C/D col=lane&15, row=(lane>>4)*4+reg (m89, R5-proven) ----
#pragma unroll
    for (int rt = 0; rt < 2; rt++)
#pragma unroll
    for (int c = 0; c < 8; c++) {
        int col = n0 + c * 16 + (lane & 15);
        if (col < N3) {
            float bias = bh[col];
#pragma unroll
            for (int j = 0; j < 4; j++) {
                int row = m0 + wave * 32 + rt * 16 + (lane >> 4) * 4 + j;
                gh[(size_t)row * N3 + col] = acc[rt][c][j] + bias;
            }
        }
    }
}

// ---------------------------------------------------------------------------
// R5 fallback GEMM (proven): 64x128 tile, in-kernel gather. Used if ws small.
// ---------------------------------------------------------------------------
__global__ __launch_bounds__(256, 2) void gh_gemm_mfma(
    const float* __restrict__ eq, const float* __restrict__ ep,
    const float* __restrict__ fs, const float* __restrict__ fe,
    const float* __restrict__ Whh_f, const float* __restrict__ bhh_f,
    const float* __restrict__ Whh_b, const float* __restrict__ bhh_b,
    float* __restrict__ ghf, float* __restrict__ ghb)
{
    const int dir = blockIdx.z;
    const float* W  = dir ? Whh_b : Whh_f;
    const float* bh = dir ? bhh_b : bhh_f;
    float* gh = dir ? ghb : ghf;
    const int n0 = blockIdx.x * 128;
    const int m0 = blockIdx.y * 64;
    const int tid  = threadIdx.x;
    const int wave = tid >> 6;
    const int lane = tid & 63;

    __shared__ __align__(16) unsigned short Ah[64][40];
    __shared__ __align__(16) unsigned short Al[64][40];
    __shared__ __align__(16) unsigned short Bs[128][40];

    f32x4 acc[8];
#pragma unroll
    for (int c = 0; c < 8; c++) acc[c] = (f32x4){0.f, 0.f, 0.f, 0.f};

    for (int kc = 0; kc < 33; kc++) {
        const int k0 = kc * 32;
#pragma unroll
        for (int u = 0; u < 8; u++) {
            int lin = u * 256 + tid;
            int row = lin >> 5, k = lin & 31;
            int gm = m0 + row, gk = k0 + k;
            float v = 0.f;
            if (gk < HH) {
                bool isq = gm < TQ;
                const float* e = isq ? eq : ep;
                int t = isq ? gm : gm - TQ;
                if (dir == 0)            v = e[(size_t)t * 2048 + gk];
                else if (gk < 1023)      v = e[(size_t)t * 2048 + 1025 + gk];
                else if (!isq)           v = (gk == 1023) ? fs[t] : fe[t];
            }
            unsigned short h = f2bf(v);
            Ah[row][k] = h;
            Al[row][k] = f2bf(v - bf2f(h));
        }
#pragma unroll
        for (int u = 0; u < 16; u++) {
            int lin = u * 256 + tid;
            int r = lin >> 5, k = lin & 31;
            int gr = n0 + r, gk = k0 + k;
            float v = (gr < N3 && gk < HH) ? W[(size_t)gr * HH + gk] : 0.f;
            Bs[r][k] = f2bf(v);
        }
        __syncthreads();

        const int arow = wave * 16 + (lane & 15);
        const int koff = (lane >> 4) * 8;
        short8 ah = *(const short8*)&Ah[arow][koff];
        short8 al = *(const short8*)&Al[arow][koff];
#pragma unroll
        for (int c = 0; c < 8; c++) {
            short8 b = *(const short8*)&Bs[c * 16 + (lane & 15)][koff];
            acc[c] = __builtin_amdgcn_mfma_f32_16x16x32_bf16(ah, b, acc[c], 0, 0, 0);
            acc[c] = __builtin_amdgcn_mfma_f32_16x16x32_bf16(al, b, acc[c], 0, 0, 0);
        }
        __syncthreads();
    }

#pragma unroll
    for (int c = 0; c < 8; c++) {
        int col = n0 + c * 16 + (lane & 15);
        if (col < N3) {
            float bias = bh[col];
#pragma unroll
            for (int r = 0; r < 4; r++) {
                int row = m0 + wave * 16 + (lane >> 4) * 4 + r;
                gh[(size_t)row * N3 + col] = acc[c][r] + bias;
            }
        }
    }
}

// ---------------------------------------------------------------------------
// Persistent scan. 171 blocks x 256 threads, lb(256,1) — DO NOT CHANGE SHAPE.
// R1 body with p/q gate split: p-dots gated on p tags only.
// ---------------------------------------------------------------------------
__global__ __launch_bounds__(256, 1) void bigru_scan(
    const float* __restrict__ eq, const float* __restrict__ ep,
    const float* __restrict__ fs, const float* __restrict__ fe,
    const float* __restrict__ Wih_f, const float* __restrict__ bih_f,
    const float* __restrict__ Wih_b, const float* __restrict__ bih_b,
    const float* __restrict__ ghf, const float* __restrict__ ghb,
    ull* __restrict__ comm,   // [chain p|q][slot 0|1][GTOT] tagged values
    float* __restrict__ out)  // h_q (512*2048) then h_p (4096*2048)
{
    __shared__ float xsh[2][2][1024];  // [parity][chain p=0,q=1][j]

    const int tid  = threadIdx.x;
    const int wave = tid >> 6;
    const int lane = tid & 63;
    const int gbase = blockIdx.x * 12 + wave * 3;

    float wreg[9][16];
    float breg[9];
    int   dre[3], je[3];
    bool  vale[3];
#pragma unroll
    for (int e = 0; e < 3; e++) {
        int g = gbase + e;
        bool v = (g < GTOT);
        int gc = v ? g : 0;
        int dir = gc / HH;
        int j = gc % HH;
        dre[e] = dir; je[e] = j; vale[e] = v;
        const float* Wih = dir ? Wih_b : Wih_f;
        const float* bih = dir ? bih_b : bih_f;
#pragma unroll
        for (int gate = 0; gate < 3; gate++) {
            const float* wr = Wih + (size_t)(gate * HH + j) * H;
#pragma unroll
            for (int i = 0; i < 4; i++) {
                float4 w4 = *(const float4*)(wr + i * 256 + lane * 4);
                wreg[e * 3 + gate][i * 4 + 0] = w4.x;
                wreg[e * 3 + gate][i * 4 + 1] = w4.y;
                wreg[e * 3 + gate][i * 4 + 2] = w4.z;
                wreg[e * 3 + gate][i * 4 + 3] = w4.w;
            }
            breg[e * 3 + gate] = bih[gate * HH + j];
        }
    }

    int sgh[3], sh0[3], sspec[3];
#pragma unroll
    for (int e = 0; e < 3; e++) {
        sgh[e]   = __builtin_amdgcn_readfirstlane(dre[e] * GH_ELEMS + je[e]);
        sh0[e]   = __builtin_amdgcn_readfirstlane(dre[e] ? (1025 + je[e]) : je[e]);
        sspec[e] = __builtin_amdgcn_readfirstlane(
                       (dre[e] && je[e] >= 1023) ? (je[e] - 1022) : 0);
    }
    const float* ghAll = ghf;

    float ghcP[9], h0cP[3], ghcQ[9], h0cQ[3];

    auto loadP = [&](int tt, float gh9[9], float h03[3]) {
        size_t base = (size_t)(TQ + tt) * N3;
#pragma unroll
        for (int e = 0; e < 3; e++) {
#pragma unroll
            for (int gate = 0; gate < 3; gate++)
                gh9[e * 3 + gate] = ghAll[base + (size_t)sgh[e] + gate * HH];
            h03[e] = (sspec[e] == 0) ? ep[(size_t)tt * 2048 + sh0[e]]
                   : (sspec[e] == 1) ? fs[tt] : fe[tt];
        }
    };
    auto loadQ = [&](int tt, float gh9[9], float h03[3]) {
        size_t base = (size_t)tt * N3;
#pragma unroll
        for (int e = 0; e < 3; e++) {
#pragma unroll
            for (int gate = 0; gate < 3; gate++)
                gh9[e * 3 + gate] = ghAll[base + (size_t)sgh[e] + gate * HH];
            h03[e] = (sspec[e] == 0) ? eq[(size_t)tt * 2048 + sh0[e]] : 0.f;
        }
    };

    loadP(0, ghcP, h0cP);
    loadQ(0, ghcQ, h0cQ);

    ull* commP = comm;
    ull* commQ = comm + 2 * GTOT;

    // t-invariant poll indices
    int idx[8];
#pragma unroll
    for (int u = 0; u < 4; u++) {
        int j = tid + 256 * u;
        idx[2 * u]     = j;
        idx[2 * u + 1] = (j == 0) ? 1024 : (1024 + j);
    }

    for (int t = 0; t < TP; t++) {
        const bool doq = (t < TQ);
        const int par = t & 1;
        const int slot = (t + 1) & 1;
        const unsigned tag = (unsigned)t;
        ull* cp = commP + slot * GTOT;
        ull* cq = commQ + slot * GTOT;

        // ============== gather y_{t-1} -> x : P CHAIN ONLY gates ============
        if (t == 0) {
#pragma unroll
            for (int u = 0; u < 4; u++) {
                int j = tid + 256 * u;
                xsh[par][0][j] = 0.f;
                xsh[par][1][j] = 0.f;
            }
        } else {
            ull vp[8];
#pragma unroll
            for (int u = 0; u < 8; u++) vp[u] = ALOAD(&cp[idx[u]]);
            bool done = false;
            while (!done) {
                done = true;
#pragma unroll
                for (int u = 0; u < 8; u++) {
                    if ((unsigned)(vp[u] >> 32) != tag) {
                        done = false;
                        vp[u] = ALOAD(&cp[idx[u]]);
                    }
                }
            }
#pragma unroll
            for (int u = 0; u < 4; u++) {
                int j = tid + 256 * u;
                xsh[par][0][j] = __uint_as_float((unsigned)vp[2 * u]) +
                                 __uint_as_float((unsigned)vp[2 * u + 1]);
            }
        }
        __syncthreads();

        // ---- issue q polls now; checked after p-publish (latency hidden) ---
        ull vq[8];
        if (doq && t > 0) {
#pragma unroll
            for (int u = 0; u < 8; u++) vq[u] = ALOAD(&cq[idx[u]]);
            __builtin_amdgcn_sched_barrier(0);  // pin issue point
        }

        // ====== prefetch gh/h0 for t+1 (scalar path; hidden under dots) =====
        float ghnP[9], h0nP[3], ghnQ[9], h0nQ[3];
        const bool ldn = (t + 1) < TP;
        const bool ldq = (t + 1) < TQ;
        if (ldn) loadP(t + 1, ghnP, h0nP);
        if (ldq) loadQ(t + 1, ghnQ, h0nQ);

        // ========================= P dots ===================================
        float accp[9];
        {
            float x[16];
#pragma unroll
            for (int i = 0; i < 4; i++) {
                float4 x4 = *(const float4*)&xsh[par][0][i * 256 + lane * 4];
                x[i * 4 + 0] = x4.x; x[i * 4 + 1] = x4.y;
                x[i * 4 + 2] = x4.z; x[i * 4 + 3] = x4.w;
            }
#pragma unroll
            for (int r = 0; r < 9; r++) {
                float s = 0.f;
#pragma unroll
                for (int i = 0; i < 16; i++) s += wreg[r][i] * x[i];
                accp[r] = s;
            }
        }
#pragma unroll
        for (int r = 0; r < 9; r++) {
            float v = accp[r];
#pragma unroll
            for (int off = 32; off > 0; off >>= 1) v += __shfl_xor(v, off, 64);
            accp[r] = v + breg[r];
        }

        // ================ P gates; publish immediately ======================
        const ull tagout = ((ull)(unsigned)(t + 1)) << 32;
        float yP[3], yQ[3];
#pragma unroll
        for (int e = 0; e < 3; e++) {
            float r = sigm(accp[e * 3 + 0] + ghcP[e * 3 + 0]);
            float z = sigm(accp[e * 3 + 1] + ghcP[e * 3 + 1]);
            float n = fast_tanh(accp[e * 3 + 2] + r * ghcP[e * 3 + 2]);
            yP[e] = (1.f - z) * n + z * h0cP[e];
            if (lane == 0 && vale[e]) {
                ull pk = tagout | (ull)__float_as_uint(yP[e]);
                ASTORE(&commP[par * GTOT + (gbase + e)], pk);
            }
        }

        // ========================= Q chain (t < TQ) =========================
        if (doq) {
            if (t > 0) {
                bool done = false;
                while (!done) {
                    done = true;
#pragma unroll
                    for (int u = 0; u < 8; u++) {
                        if ((unsigned)(vq[u] >> 32) != tag) {
                            done = false;
                            vq[u] = ALOAD(&cq[idx[u]]);
                        }
                    }
                }
#pragma unroll
                for (int u = 0; u < 4; u++) {
                    int j = tid + 256 * u;
                    xsh[par][1][j] = __uint_as_float((unsigned)vq[2 * u]) +
                                     __uint_as_float((unsigned)vq[2 * u + 1]);
                }
            }
            __syncthreads();

            float accq[9];
            {
                float x[16];
#pragma unroll
                for (int i = 0; i < 4; i++) {
                    float4 x4 = *(const float4*)&xsh[par][1][i * 256 + lane * 4];
                    x[i * 4 + 0] = x4.x; x[i * 4 + 1] = x4.y;
                    x[i * 4 + 2] = x4.z; x[i * 4 + 3] = x4.w;
                }
#pragma unroll
                for (int r = 0; r < 9; r++) {
                    float s = 0.f;
#pragma unroll
                    for (int i = 0; i < 16; i++) s += wreg[r][i] * x[i];
#pragma unroll
                    for (int off = 32; off > 0; off >>= 1) s += __shfl_xor(s, off, 64);
                    accq[r] = s + breg[r];
                }
            }
#pragma unroll
            for (int e = 0; e < 3; e++) {
                float r = sigm(accq[e * 3 + 0] + ghcQ[e * 3 + 0]);
                float z = sigm(accq[e * 3 + 1] + ghcQ[e * 3 + 1]);
                float n = fast_tanh(accq[e * 3 + 2] + r * ghcQ[e * 3 + 2]);
                yQ[e] = (1.f - z) * n + z * h0cQ[e];
                if (lane == 0 && vale[e]) {
                    ull pk = tagout | (ull)__float_as_uint(yQ[e]);
                    ASTORE(&commQ[par * GTOT + (gbase + e)], pk);
                }
            }
        }

        // ==================== out stores (off critical path) ================
        if (lane == 0) {
#pragma unroll
            for (int e = 0; e < 3; e++) {
                if (vale[e] && je[e] < H) {
                    out[(size_t)TQ * 2048 + (size_t)t * 2048 + dre[e] * H + je[e]] = yP[e];
                    if (doq)
                        out[(size_t)t * 2048 + dre[e] * H + je[e]] = yQ[e];
                }
            }
        }

        // rotate pipeline registers
        if (ldn) {
#pragma unroll
            for (int i = 0; i < 9; i++) ghcP[i] = ghnP[i];
#pragma unroll
            for (int e = 0; e < 3; e++) h0cP[e] = h0nP[e];
        }
        if (ldq) {
#pragma unroll
            for (int i = 0; i < 9; i++) ghcQ[i] = ghnQ[i];
#pragma unroll
            for (int e = 0; e < 3; e++) h0cQ[e] = h0nQ[e];
        }
    }
}

extern "C" void kernel_launch(void* const* d_in, const int* in_sizes, int n_in,
                              void* d_out, int out_size, void* d_ws, size_t ws_size,
                              hipStream_t stream) {
    const float* eq    = (const float*)d_in[0];
    const float* ep    = (const float*)d_in[1];
    const float* fs    = (const float*)d_in[2];
    const float* fe    = (const float*)d_in[3];
    const float* Wih_f = (const float*)d_in[4];
    const float* Whh_f = (const float*)d_in[5];
    const float* bih_f = (const float*)d_in[6];
    const float* bhh_f = (const float*)d_in[7];
    const float* Wih_b = (const float*)d_in[8];
    const float* Whh_b = (const float*)d_in[9];
    const float* bih_b = (const float*)d_in[10];
    const float* bhh_b = (const float*)d_in[11];
    float* out = (float*)d_out;

    float* ghf = (float*)d_ws;
    float* ghb = ghf + (size_t)GH_ELEMS;
    size_t commOff = ((2 * (size_t)GH_ELEMS * sizeof(float)) + 4095) & ~(size_t)4095;
    ull* comm = (ull*)((char*)d_ws + commOff);
    size_t abfOff = (commOff + (size_t)4 * GTOT * sizeof(ull) + 4095) & ~(size_t)4095;
    size_t abfBytes = 2 * ATOT * sizeof(unsigned short);
    unsigned short* abf = (unsigned short*)((char*)d_ws + abfOff);
    const bool fastOK = (ws_size >= abfOff + abfBytes);

    hipMemsetAsync(comm, 0, (size_t)4 * GTOT * sizeof(ull), stream);

    if (fastOK) {
        int prepBlocks = (MTOT * 2 * (AKP / 8) + 255) / 256;
        prep_abf<<<dim3(prepBlocks), 256, 0, stream>>>(eq, ep, fs, fe, abf);
        gh_gemm_fast<<<dim3((N3 + 127) / 128, MTOT / 128, 2), 256, 0, stream>>>(
            abf, Whh_f, bhh_f, Whh_b, bhh_b, ghf, ghb);
    } else {
        gh_gemm_mfma<<<dim3((N3 + 127) / 128, MTOT / 64, 2), 256, 0, stream>>>(
            eq, ep, fs, fe, Whh_f, bhh_f, Whh_b, bhh_b, ghf, ghb);
    }

    bigru_scan<<<dim3(171), dim3(256), 0, stream>>>(
        eq, ep, fs, fe, Wih_f, bih_f, Wih_b, bih_b, ghf, ghb, comm, out);
}

// Round 8
// 13575.854 us; speedup vs baseline: 1.2147x; 1.2147x over previous
//
#include <hip/hip_runtime.h>
#include <stdint.h>

// BiGRU scan, H=1024. Round 8: bank the proven combination.
//  - Scan: BYTE-EXACT R1/R5 kernel (171x256, lb(256,1), 204 VGPR, 12.80 ms).
//    LESSON R2/R3/R4/R7: the 204-VGPR no-spill allocation is a property of
//    this exact control-flow structure. Reordering live ranges (R7's p/q
//    split) or changing block shape re-trips the 128/120-VGPR spill.
//  - gh GEMM: R7's proven prep_abf + gh_gemm_fast (0.64 ms incl. overhead,
//    absmax bit-identical to R5). Fallback to R5 GEMM if workspace small.

#define H    1024
#define HH   1025
#define N3   3075
#define TQ   512
#define TP   4096
#define MTOT 4608
#define GTOT 2050
#define GH_ELEMS (MTOT * N3)
#define AKP  1056                               // padded K (33 chunks of 32)
#define ATOT ((size_t)MTOT * 2 * AKP)           // shorts per plane (hi or lo)

typedef unsigned long long ull;
typedef __attribute__((ext_vector_type(8))) short short8;
typedef __attribute__((ext_vector_type(4))) float f32x4;

__device__ __forceinline__ float sigm(float x) { return 1.f / (1.f + __expf(-x)); }
__device__ __forceinline__ float fast_tanh(float x) {
    float e = __expf(2.f * x);
    return (e - 1.f) / (e + 1.f);
}
__device__ __forceinline__ unsigned short f2bf(float f) {
    unsigned u = __float_as_uint(f);
    unsigned r = (u + 0x7FFFu + ((u >> 16) & 1u)) >> 16;
    return (unsigned short)r;
}
__device__ __forceinline__ float bf2f(unsigned short h) {
    return __uint_as_float(((unsigned)h) << 16);
}

// ---------------------------------------------------------------------------
// Prep: h0 -> bf16 hi/lo planes, padded to AKP. (R7-proven)
// ---------------------------------------------------------------------------
__global__ __launch_bounds__(256) void prep_abf(
    const float* __restrict__ eq, const float* __restrict__ ep,
    const float* __restrict__ fs, const float* __restrict__ fe,
    unsigned short* __restrict__ abf)
{
    const int K8 = AKP / 8;                    // 132 groups of 8 k
    int idx = blockIdx.x * 256 + threadIdx.x;
    int rowid = idx / K8;
    if (rowid >= MTOT * 2) return;
    int k0 = (idx - rowid * K8) * 8;
    int dir = rowid & 1;
    int m = rowid >> 1;
    bool isq = m < TQ;
    const float* e = isq ? eq : ep;
    int t = isq ? m : m - TQ;

    short8 hi, lo;
#pragma unroll
    for (int j = 0; j < 8; j++) {
        int gk = k0 + j;
        float v = 0.f;
        if (gk < HH) {
            if (dir == 0)            v = e[(size_t)t * 2048 + gk];
            else if (gk < 1023)      v = e[(size_t)t * 2048 + 1025 + gk];
            else if (!isq)           v = (gk == 1023) ? fs[t] : fe[t];
        }
        unsigned short h = f2bf(v);
        hi[j] = (short)h;
        lo[j] = (short)f2bf(v - bf2f(h));
    }
    size_t base = (size_t)rowid * AKP + k0;    // 16B-aligned (k0 mult of 8)
    *(short8*)&abf[base] = hi;
    *(short8*)&abf[ATOT + base] = lo;
}

// ---------------------------------------------------------------------------
// Fast MFMA gh GEMM: 128M x 128N tile, K-chunks of 32. (R7-proven, 0.64 ms)
// ---------------------------------------------------------------------------
__global__ __launch_bounds__(256, 2) void gh_gemm_fast(
    const unsigned short* __restrict__ abf,
    const float* __restrict__ Whh_f, const float* __restrict__ bhh_f,
    const float* __restrict__ Whh_b, const float* __restrict__ bhh_b,
    float* __restrict__ ghf, float* __restrict__ ghb)
{
    const int dir = blockIdx.z;
    const float* W  = dir ? Whh_b : Whh_f;
    const float* bh = dir ? bhh_b : bhh_f;
    float* gh = dir ? ghb : ghf;
    const int n0 = blockIdx.x * 128;
    const int m0 = blockIdx.y * 128;
    const int tid = threadIdx.x, wave = tid >> 6, lane = tid & 63;

    __shared__ __align__(16) unsigned short Ah[128][40];
    __shared__ __align__(16) unsigned short Al[128][40];
    __shared__ __align__(16) unsigned short Bs[128][40];

    f32x4 acc[2][8];
#pragma unroll
    for (int rt = 0; rt < 2; rt++)
#pragma unroll
        for (int c = 0; c < 8; c++) acc[rt][c] = (f32x4){0.f, 0.f, 0.f, 0.f};

    for (int kc = 0; kc < 33; kc++) {
        const int k0 = kc * 32;
        // ---- stage A hi/lo: thread -> row tid>>1, half (tid&1)*16 ----
        {
            int r = tid >> 1, h16 = (tid & 1) * 16;
            size_t arow = ((size_t)(m0 + r) * 2 + dir) * AKP + k0 + h16;
            short8 v0 = *(const short8*)&abf[arow];
            short8 v1 = *(const short8*)&abf[arow + 8];
            *(short8*)&Ah[r][h16]     = v0;
            *(short8*)&Ah[r][h16 + 8] = v1;
            short8 u0 = *(const short8*)&abf[ATOT + arow];
            short8 u1 = *(const short8*)&abf[ATOT + arow + 8];
            *(short8*)&Al[r][h16]     = u0;
            *(short8*)&Al[r][h16 + 8] = u1;
        }
        // ---- stage B (coalesced scalar convert) ----
#pragma unroll
        for (int u = 0; u < 16; u++) {
            int lin = u * 256 + tid;
            int r = lin >> 5, k = lin & 31;
            int gr = n0 + r, gk = k0 + k;
            float v = (gr < N3 && gk < HH) ? W[(size_t)gr * HH + gk] : 0.f;
            Bs[r][k] = f2bf(v);
        }
        __syncthreads();

        const int rA0 = wave * 32 + (lane & 15);
        const int ko  = (lane >> 4) * 8;
        short8 ah0 = *(const short8*)&Ah[rA0][ko];
        short8 ah1 = *(const short8*)&Ah[rA0 + 16][ko];
        short8 al0 = *(const short8*)&Al[rA0][ko];
        short8 al1 = *(const short8*)&Al[rA0 + 16][ko];
#pragma unroll
        for (int c = 0; c < 8; c++) {
            short8 b = *(const short8*)&Bs[c * 16 + (lane & 15)][ko];
            acc[0][c] = __builtin_amdgcn_mfma_f32_16x16x32_bf16(ah0, b, acc[0][c], 0, 0, 0);
            acc[0][c] = __builtin_amdgcn_mfma_f32_16x16x32_bf16(al0, b, acc[0][c], 0, 0, 0);
            acc[1][c] = __builtin_amdgcn_mfma_f32_16x16x32_bf16(ah1, b, acc[1][c], 0, 0, 0);
            acc[1][c] = __builtin_amdgcn_mfma_f32_16x16x32_bf16(al1, b, acc[1][c], 0, 0, 0);
        }
        __syncthreads();
    }

    // ---- epilogue: C/D col=lane&15, row=(lane>>4)*4+reg (m89-verified) ----
#pragma unroll
    for (int rt = 0; rt < 2; rt++)
#pragma unroll
    for (int c = 0; c < 8; c++) {
        int col = n0 + c * 16 + (lane & 15);
        if (col < N3) {
            float bias = bh[col];
#pragma unroll
            for (int j = 0; j < 4; j++) {
                int row = m0 + wave * 32 + rt * 16 + (lane >> 4) * 4 + j;
                gh[(size_t)row * N3 + col] = acc[rt][c][j] + bias;
            }
        }
    }
}

// ---------------------------------------------------------------------------
// R5 fallback GEMM (proven): 64x128 tile, in-kernel gather. Used if ws small.
// ---------------------------------------------------------------------------
__global__ __launch_bounds__(256, 2) void gh_gemm_mfma(
    const float* __restrict__ eq, const float* __restrict__ ep,
    const float* __restrict__ fs, const float* __restrict__ fe,
    const float* __restrict__ Whh_f, const float* __restrict__ bhh_f,
    const float* __restrict__ Whh_b, const float* __restrict__ bhh_b,
    float* __restrict__ ghf, float* __restrict__ ghb)
{
    const int dir = blockIdx.z;
    const float* W  = dir ? Whh_b : Whh_f;
    const float* bh = dir ? bhh_b : bhh_f;
    float* gh = dir ? ghb : ghf;
    const int n0 = blockIdx.x * 128;
    const int m0 = blockIdx.y * 64;
    const int tid  = threadIdx.x;
    const int wave = tid >> 6;
    const int lane = tid & 63;

    __shared__ __align__(16) unsigned short Ah[64][40];
    __shared__ __align__(16) unsigned short Al[64][40];
    __shared__ __align__(16) unsigned short Bs[128][40];

    f32x4 acc[8];
#pragma unroll
    for (int c = 0; c < 8; c++) acc[c] = (f32x4){0.f, 0.f, 0.f, 0.f};

    for (int kc = 0; kc < 33; kc++) {
        const int k0 = kc * 32;
#pragma unroll
        for (int u = 0; u < 8; u++) {
            int lin = u * 256 + tid;
            int row = lin >> 5, k = lin & 31;
            int gm = m0 + row, gk = k0 + k;
            float v = 0.f;
            if (gk < HH) {
                bool isq = gm < TQ;
                const float* e = isq ? eq : ep;
                int t = isq ? gm : gm - TQ;
                if (dir == 0)            v = e[(size_t)t * 2048 + gk];
                else if (gk < 1023)      v = e[(size_t)t * 2048 + 1025 + gk];
                else if (!isq)           v = (gk == 1023) ? fs[t] : fe[t];
            }
            unsigned short h = f2bf(v);
            Ah[row][k] = h;
            Al[row][k] = f2bf(v - bf2f(h));
        }
#pragma unroll
        for (int u = 0; u < 16; u++) {
            int lin = u * 256 + tid;
            int r = lin >> 5, k = lin & 31;
            int gr = n0 + r, gk = k0 + k;
            float v = (gr < N3 && gk < HH) ? W[(size_t)gr * HH + gk] : 0.f;
            Bs[r][k] = f2bf(v);
        }
        __syncthreads();

        const int arow = wave * 16 + (lane & 15);
        const int koff = (lane >> 4) * 8;
        short8 ah = *(const short8*)&Ah[arow][koff];
        short8 al = *(const short8*)&Al[arow][koff];
#pragma unroll
        for (int c = 0; c < 8; c++) {
            short8 b = *(const short8*)&Bs[c * 16 + (lane & 15)][koff];
            acc[c] = __builtin_amdgcn_mfma_f32_16x16x32_bf16(ah, b, acc[c], 0, 0, 0);
            acc[c] = __builtin_amdgcn_mfma_f32_16x16x32_bf16(al, b, acc[c], 0, 0, 0);
        }
        __syncthreads();
    }

#pragma unroll
    for (int c = 0; c < 8; c++) {
        int col = n0 + c * 16 + (lane & 15);
        if (col < N3) {
            float bias = bh[col];
#pragma unroll
            for (int r = 0; r < 4; r++) {
                int row = m0 + wave * 16 + (lane >> 4) * 4 + r;
                gh[(size_t)row * N3 + col] = acc[c][r] + bias;
            }
        }
    }
}

// ---------------------------------------------------------------------------
// Persistent scan. 171 blocks x 256 threads; wave w of block b owns output
// elems g = b*12 + w*3 + {0,1,2}. Lane l holds Wih[row][4l + 256i + m].
// BYTE-EXACT R1/R5 kernel (204 VGPR, 12.80 ms steady). Do not modify.
// ---------------------------------------------------------------------------
__global__ __launch_bounds__(256, 1) void bigru_scan(
    const float* __restrict__ eq, const float* __restrict__ ep,
    const float* __restrict__ fs, const float* __restrict__ fe,
    const float* __restrict__ Wih_f, const float* __restrict__ bih_f,
    const float* __restrict__ Wih_b, const float* __restrict__ bih_b,
    const float* __restrict__ ghf, const float* __restrict__ ghb,
    ull* __restrict__ comm,   // [chain p|q][slot 0|1][GTOT] tagged values
    float* __restrict__ out)  // h_q (512*2048) then h_p (4096*2048)
{
    __shared__ float xsh[2][2][1024];  // [parity][chain p=0,q=1][j]

    const int tid  = threadIdx.x;
    const int wave = tid >> 6;
    const int lane = tid & 63;
    const int gbase = blockIdx.x * 12 + wave * 3;

    // ---- register-resident weights ----
    float wreg[9][16];
    float breg[9];
    int   dre[3], je[3];
    bool  vale[3];
#pragma unroll
    for (int e = 0; e < 3; e++) {
        int g = gbase + e;
        bool v = (g < GTOT);
        int gc = v ? g : 0;
        int dir = gc / HH;
        int j = gc % HH;
        dre[e] = dir; je[e] = j; vale[e] = v;
        const float* Wih = dir ? Wih_b : Wih_f;
        const float* bih = dir ? bih_b : bih_f;
#pragma unroll
        for (int gate = 0; gate < 3; gate++) {
            const float* wr = Wih + (size_t)(gate * HH + j) * H;
#pragma unroll
            for (int i = 0; i < 4; i++) {
                float4 w4 = *(const float4*)(wr + i * 256 + lane * 4);
                wreg[e * 3 + gate][i * 4 + 0] = w4.x;
                wreg[e * 3 + gate][i * 4 + 1] = w4.y;
                wreg[e * 3 + gate][i * 4 + 2] = w4.z;
                wreg[e * 3 + gate][i * 4 + 3] = w4.w;
            }
            breg[e * 3 + gate] = bih[gate * HH + j];
        }
    }

    // ---- scalarized (wave-uniform) per-e offsets for the gh/h0 pipeline ----
    int sgh[3], sh0[3], sspec[3];
#pragma unroll
    for (int e = 0; e < 3; e++) {
        sgh[e]   = __builtin_amdgcn_readfirstlane(dre[e] * GH_ELEMS + je[e]);
        sh0[e]   = __builtin_amdgcn_readfirstlane(dre[e] ? (1025 + je[e]) : je[e]);
        sspec[e] = __builtin_amdgcn_readfirstlane(
                       (dre[e] && je[e] >= 1023) ? (je[e] - 1022) : 0);
    }
    const float* ghAll = ghf;  // ghb is contiguous at ghf + GH_ELEMS

    // ---- gh/h0 register pipeline (one step ahead) ----
    float ghcP[9], h0cP[3], ghcQ[9], h0cQ[3];

    auto loadP = [&](int tt, float gh9[9], float h03[3]) {
        size_t base = (size_t)(TQ + tt) * N3;
#pragma unroll
        for (int e = 0; e < 3; e++) {
#pragma unroll
            for (int gate = 0; gate < 3; gate++)
                gh9[e * 3 + gate] = ghAll[base + (size_t)sgh[e] + gate * HH];
            h03[e] = (sspec[e] == 0) ? ep[(size_t)tt * 2048 + sh0[e]]
                   : (sspec[e] == 1) ? fs[tt] : fe[tt];
        }
    };
    auto loadQ = [&](int tt, float gh9[9], float h03[3]) {
        size_t base = (size_t)tt * N3;
#pragma unroll
        for (int e = 0; e < 3; e++) {
#pragma unroll
            for (int gate = 0; gate < 3; gate++)
                gh9[e * 3 + gate] = ghAll[base + (size_t)sgh[e] + gate * HH];
            h03[e] = (sspec[e] == 0) ? eq[(size_t)tt * 2048 + sh0[e]] : 0.f;
        }
    };

    loadP(0, ghcP, h0cP);
    loadQ(0, ghcQ, h0cQ);

    ull* commP = comm;
    ull* commQ = comm + 2 * GTOT;

    for (int t = 0; t < TP; t++) {
        const bool doq = (t < TQ);
        const int par = t & 1;

        // ================= gather y_{t-1} -> x (polls FIRST) ================
        if (t == 0) {
#pragma unroll
            for (int u = 0; u < 4; u++) {
                int j = tid + 256 * u;
                xsh[par][0][j] = 0.f;
                xsh[par][1][j] = 0.f;
            }
        } else {
            const int slot = (t + 1) & 1;     // (t-1) % 2
            const unsigned tag = (unsigned)t; // y_{t-1} carries tag t
            ull* cp = commP + slot * GTOT;
            ull* cq = commQ + slot * GTOT;
            int idx[8];
#pragma unroll
            for (int u = 0; u < 4; u++) {
                int j = tid + 256 * u;
                idx[2 * u]     = j;                                // yf[j]
                idx[2 * u + 1] = (j == 0) ? 1024 : (1025 + j - 1); // yb[j-1]
            }
            ull vp[8], vq[8];
#pragma unroll
            for (int u = 0; u < 8; u++)
                vp[u] = __hip_atomic_load(&cp[idx[u]], __ATOMIC_RELAXED, __HIP_MEMORY_SCOPE_AGENT);
            if (doq) {
#pragma unroll
                for (int u = 0; u < 8; u++)
                    vq[u] = __hip_atomic_load(&cq[idx[u]], __ATOMIC_RELAXED, __HIP_MEMORY_SCOPE_AGENT);
            }
            // batch retry: one LLC latency per round, p+q overlapped
            bool done = false;
            while (!done) {
                done = true;
#pragma unroll
                for (int u = 0; u < 8; u++) {
                    if ((unsigned)(vp[u] >> 32) != tag) {
                        done = false;
                        vp[u] = __hip_atomic_load(&cp[idx[u]], __ATOMIC_RELAXED, __HIP_MEMORY_SCOPE_AGENT);
                    }
                }
                if (doq) {
#pragma unroll
                    for (int u = 0; u < 8; u++) {
                        if ((unsigned)(vq[u] >> 32) != tag) {
                            done = false;
                            vq[u] = __hip_atomic_load(&cq[idx[u]], __ATOMIC_RELAXED, __HIP_MEMORY_SCOPE_AGENT);
                        }
                    }
                }
            }
#pragma unroll
            for (int u = 0; u < 4; u++) {
                int j = tid + 256 * u;
                xsh[par][0][j] = __uint_as_float((unsigned)vp[2 * u]) +
                                 __uint_as_float((unsigned)vp[2 * u + 1]);
            }
            if (doq) {
#pragma unroll
                for (int u = 0; u < 4; u++) {
                    int j = tid + 256 * u;
                    xsh[par][1][j] = __uint_as_float((unsigned)vq[2 * u]) +
                                     __uint_as_float((unsigned)vq[2 * u + 1]);
                }
            }
        }
        __syncthreads();

        // ====== prefetch gh/h0 for t+1 (scalar path; hidden under dots) =====
        float ghnP[9], h0nP[3], ghnQ[9], h0nQ[3];
        const bool ldn = (t + 1) < TP;
        const bool ldq = (t + 1) < TQ;
        if (ldn) loadP(t + 1, ghnP, h0nP);
        if (ldq) loadQ(t + 1, ghnQ, h0nQ);

        // ========================= dot products =============================
        float accp[9];
        {
            float x[16];
#pragma unroll
            for (int i = 0; i < 4; i++) {
                float4 x4 = *(const float4*)&xsh[par][0][i * 256 + lane * 4];
                x[i * 4 + 0] = x4.x; x[i * 4 + 1] = x4.y;
                x[i * 4 + 2] = x4.z; x[i * 4 + 3] = x4.w;
            }
#pragma unroll
            for (int r = 0; r < 9; r++) {
                float s = 0.f;
#pragma unroll
                for (int i = 0; i < 16; i++) s += wreg[r][i] * x[i];
                accp[r] = s;
            }
        }
#pragma unroll
        for (int r = 0; r < 9; r++) {
            float v = accp[r];
#pragma unroll
            for (int off = 32; off > 0; off >>= 1) v += __shfl_xor(v, off, 64);
            accp[r] = v + breg[r];
        }

        float accq[9];
        if (doq) {
            float x[16];
#pragma unroll
            for (int i = 0; i < 4; i++) {
                float4 x4 = *(const float4*)&xsh[par][1][i * 256 + lane * 4];
                x[i * 4 + 0] = x4.x; x[i * 4 + 1] = x4.y;
                x[i * 4 + 2] = x4.z; x[i * 4 + 3] = x4.w;
            }
#pragma unroll
            for (int r = 0; r < 9; r++) {
                float s = 0.f;
#pragma unroll
                for (int i = 0; i < 16; i++) s += wreg[r][i] * x[i];
#pragma unroll
                for (int off = 32; off > 0; off >>= 1) s += __shfl_xor(s, off, 64);
                accq[r] = s + breg[r];
            }
        }

        // ================ gates; publish comm FIRST, out after ==============
        const ull tagout = ((ull)(unsigned)(t + 1)) << 32;
        float yP[3], yQ[3];
#pragma unroll
        for (int e = 0; e < 3; e++) {
            float r = sigm(accp[e * 3 + 0] + ghcP[e * 3 + 0]);
            float z = sigm(accp[e * 3 + 1] + ghcP[e * 3 + 1]);
            float n = fast_tanh(accp[e * 3 + 2] + r * ghcP[e * 3 + 2]);
            yP[e] = (1.f - z) * n + z * h0cP[e];
            if (lane == 0 && vale[e]) {
                ull pk = tagout | (ull)__float_as_uint(yP[e]);
                __hip_atomic_store(&commP[par * GTOT + (gbase + e)], pk,
                                   __ATOMIC_RELAXED, __HIP_MEMORY_SCOPE_AGENT);
            }
        }
        if (doq) {
#pragma unroll
            for (int e = 0; e < 3; e++) {
                float r = sigm(accq[e * 3 + 0] + ghcQ[e * 3 + 0]);
                float z = sigm(accq[e * 3 + 1] + ghcQ[e * 3 + 1]);
                float n = fast_tanh(accq[e * 3 + 2] + r * ghcQ[e * 3 + 2]);
                yQ[e] = (1.f - z) * n + z * h0cQ[e];
                if (lane == 0 && vale[e]) {
                    ull pk = tagout | (ull)__float_as_uint(yQ[e]);
                    __hip_atomic_store(&commQ[par * GTOT + (gbase + e)], pk,
                                       __ATOMIC_RELAXED, __HIP_MEMORY_SCOPE_AGENT);
                }
            }
        }
        // out stores (off the critical path)
        if (lane == 0) {
#pragma unroll
            for (int e = 0; e < 3; e++) {
                if (vale[e] && je[e] < H) {
                    out[(size_t)TQ * 2048 + (size_t)t * 2048 + dre[e] * H + je[e]] = yP[e];
                    if (doq)
                        out[(size_t)t * 2048 + dre[e] * H + je[e]] = yQ[e];
                }
            }
        }

        // rotate pipeline registers
        if (ldn) {
#pragma unroll
            for (int i = 0; i < 9; i++) ghcP[i] = ghnP[i];
#pragma unroll
            for (int e = 0; e < 3; e++) h0cP[e] = h0nP[e];
        }
        if (ldq) {
#pragma unroll
            for (int i = 0; i < 9; i++) ghcQ[i] = ghnQ[i];
#pragma unroll
            for (int e = 0; e < 3; e++) h0cQ[e] = h0nQ[e];
        }
    }
}

extern "C" void kernel_launch(void* const* d_in, const int* in_sizes, int n_in,
                              void* d_out, int out_size, void* d_ws, size_t ws_size,
                              hipStream_t stream) {
    const float* eq    = (const float*)d_in[0];
    const float* ep    = (const float*)d_in[1];
    const float* fs    = (const float*)d_in[2];
    const float* fe    = (const float*)d_in[3];
    const float* Wih_f = (const float*)d_in[4];
    const float* Whh_f = (const float*)d_in[5];
    const float* bih_f = (const float*)d_in[6];
    const float* bhh_f = (const float*)d_in[7];
    const float* Wih_b = (const float*)d_in[8];
    const float* Whh_b = (const float*)d_in[9];
    const float* bih_b = (const float*)d_in[10];
    const float* bhh_b = (const float*)d_in[11];
    float* out = (float*)d_out;

    float* ghf = (float*)d_ws;
    float* ghb = ghf + (size_t)GH_ELEMS;
    size_t commOff = ((2 * (size_t)GH_ELEMS * sizeof(float)) + 4095) & ~(size_t)4095;
    ull* comm = (ull*)((char*)d_ws + commOff);
    size_t abfOff = (commOff + (size_t)4 * GTOT * sizeof(ull) + 4095) & ~(size_t)4095;
    size_t abfBytes = 2 * ATOT * sizeof(unsigned short);
    unsigned short* abf = (unsigned short*)((char*)d_ws + abfOff);
    const bool fastOK = (ws_size >= abfOff + abfBytes);

    hipMemsetAsync(comm, 0, (size_t)4 * GTOT * sizeof(ull), stream);

    if (fastOK) {
        int prepBlocks = (MTOT * 2 * (AKP / 8) + 255) / 256;
        prep_abf<<<dim3(prepBlocks), 256, 0, stream>>>(eq, ep, fs, fe, abf);
        gh_gemm_fast<<<dim3((N3 + 127) / 128, MTOT / 128, 2), 256, 0, stream>>>(
            abf, Whh_f, bhh_f, Whh_b, bhh_b, ghf, ghb);
    } else {
        gh_gemm_mfma<<<dim3((N3 + 127) / 128, MTOT / 64, 2), 256, 0, stream>>>(
            eq, ep, fs, fe, Whh_f, bhh_f, Whh_b, bhh_b, ghf, ghb);
    }

    bigru_scan<<<dim3(171), dim3(256), 0, stream>>>(
        eq, ep, fs, fe, Wih_f, bih_f, Wih_b, bih_b, ghf, ghb, comm, out);
}